// Round 1
// baseline (400.248 us; speedup 1.0000x reference)
//
#include <hip/hip_runtime.h>
#include <cstdint>
#include <cstddef>

typedef unsigned short u16;
typedef __attribute__((ext_vector_type(8))) __bf16 bf16x8;
typedef __attribute__((ext_vector_type(4))) float f32x4;
typedef __attribute__((ext_vector_type(4))) unsigned short u16x4;

#define DEV __device__ __forceinline__

DEV u16 f2bf(float f) {
  union { float f; unsigned u; } v; v.f = f;
  unsigned r = v.u + 0x7fffu + ((v.u >> 16) & 1u);   // RNE
  return (u16)(r >> 16);
}

DEV void gload_lds16(const void* g, void* l) {
  __builtin_amdgcn_global_load_lds(
      (const __attribute__((address_space(1))) void*)g,
      (__attribute__((address_space(3))) void*)l, 16, 0, 0);
}

DEV float gelu_f(float x) {
  float u = 0.7978845608028654f * (x + 0.044715f * x * x * x);
  return 0.5f * x * (1.0f + tanhf(u));
}

// ---------------- fp32 -> bf16 transposed weight: Wt[n][k] = W[k][n] ----------------
__global__ __launch_bounds__(256) void wtrans(const float* __restrict__ W,
                                              u16* __restrict__ Wt, int K, int N) {
  __shared__ float tile[32][33];
  const int n0 = blockIdx.x * 32, k0 = blockIdx.y * 32;
  const int t = threadIdx.x, c = t & 31, r0 = t >> 5;
#pragma unroll
  for (int i = 0; i < 4; ++i) {
    int r = r0 + i * 8;
    tile[r][c] = W[(size_t)(k0 + r) * N + n0 + c];
  }
  __syncthreads();
#pragma unroll
  for (int i = 0; i < 4; ++i) {
    int r = r0 + i * 8;
    Wt[(size_t)(n0 + r) * K + k0 + c] = f2bf(tile[c][r]);
  }
}

// ---------------- bf16 V transpose: v[B,T,H,HD] (ld=ldv) -> vt[BH*64, T] ----------------
__global__ __launch_bounds__(256) void vtrans(const u16* __restrict__ v,
                                              u16* __restrict__ vt, int ldv) {
  __shared__ u16 tile[32][33];
  const int t0 = blockIdx.x * 32;
  const int d0 = blockIdx.y * 32;
  const int bh = blockIdx.z, b = bh >> 4, h = bh & 15;
  const int t = threadIdx.x, c = t & 31, r0 = t >> 5;
#pragma unroll
  for (int i = 0; i < 4; ++i) {
    int r = r0 + i * 8;
    tile[r][c] = v[(size_t)(b * 2048 + t0 + r) * ldv + h * 64 + d0 + c];
  }
  __syncthreads();
#pragma unroll
  for (int i = 0; i < 4; ++i) {
    int r = r0 + i * 8;
    vt[(size_t)(bh * 64 + d0 + r) * 2048 + t0 + c] = tile[c][r];
  }
}

// ---------------- LayerNorm fp32 -> bf16 (one row of 1024 per block) ----------------
__global__ __launch_bounds__(256) void ln_bf16(const float* __restrict__ x,
                                               const float* __restrict__ g,
                                               const float* __restrict__ s,
                                               u16* __restrict__ out) {
  const int row = blockIdx.x, t = threadIdx.x;
  const int l = t & 63, w = t >> 6;
  f32x4 v = *(const f32x4*)(x + (size_t)row * 1024 + t * 4);
  float sm = v.x + v.y + v.z + v.w;
  float s2 = v.x * v.x + v.y * v.y + v.z * v.z + v.w * v.w;
#pragma unroll
  for (int d = 1; d < 64; d <<= 1) { sm += __shfl_xor(sm, d); s2 += __shfl_xor(s2, d); }
  __shared__ float red[8];
  if (l == 0) { red[w] = sm; red[4 + w] = s2; }
  __syncthreads();
  sm = red[0] + red[1] + red[2] + red[3];
  s2 = red[4] + red[5] + red[6] + red[7];
  const float mean = sm * (1.0f / 1024.0f);
  const float rstd = rsqrtf(s2 * (1.0f / 1024.0f) - mean * mean + 1e-5f);
  f32x4 gv = *(const f32x4*)(g + t * 4);
  f32x4 sv = *(const f32x4*)(s + t * 4);
  u16x4 o;
  o.x = f2bf((v.x - mean) * rstd * gv.x + sv.x);
  o.y = f2bf((v.y - mean) * rstd * gv.y + sv.y);
  o.z = f2bf((v.z - mean) * rstd * gv.z + sv.z);
  o.w = f2bf((v.w - mean) * rstd * gv.w + sv.w);
  *(u16x4*)(out + (size_t)row * 1024 + t * 4) = o;
}

// ---------------- GEMM C = A[M,K](bf16) * Bt[N,K]^T(bf16), m97 structure ----------------
// EPI: 0 = store bf16 ; 1 = bf16(gelu(acc+bias)) ; 2 = f32(acc + bias + resid)
template <int EPI>
__global__ __launch_bounds__(256) void gemm_bt(const u16* __restrict__ A,
                                               const u16* __restrict__ Bt,
                                               const float* __restrict__ bias,
                                               const float* __restrict__ resid,
                                               void* __restrict__ outp,
                                               int M, int N, int K) {
  __shared__ alignas(16) u16 As[128 * 32];
  __shared__ alignas(16) u16 Bs[128 * 32];
  const int tid = threadIdx.x, l = tid & 63, w = tid >> 6;
  const int bm0 = blockIdx.x * 128, bn0 = blockIdx.y * 128;
  const int wm = (w >> 1) * 64, wn = (w & 1) * 64;
  const int lr = l & 15, lk8 = (l >> 4) * 8;

  f32x4 acc[4][4];
#pragma unroll
  for (int i = 0; i < 4; ++i)
#pragma unroll
    for (int j = 0; j < 4; ++j) acc[i][j] = (f32x4){0.f, 0.f, 0.f, 0.f};

  for (int k0 = 0; k0 < K; k0 += 32) {
#pragma unroll
    for (int c = 0; c < 2; ++c) {
      const int lin = c * 256 + tid;
      const int row = lin >> 2, col = (lin & 3) * 8;
      gload_lds16(A + (size_t)(bm0 + row) * K + k0 + col, (char*)As + lin * 16);
      gload_lds16(Bt + (size_t)(bn0 + row) * K + k0 + col, (char*)Bs + lin * 16);
    }
    __syncthreads();
    bf16x8 af[4], bfv[4];
#pragma unroll
    for (int i = 0; i < 4; ++i) af[i] = *(const bf16x8*)(As + (wm + i * 16 + lr) * 32 + lk8);
#pragma unroll
    for (int j = 0; j < 4; ++j) bfv[j] = *(const bf16x8*)(Bs + (wn + j * 16 + lr) * 32 + lk8);
#pragma unroll
    for (int i = 0; i < 4; ++i)
#pragma unroll
      for (int j = 0; j < 4; ++j)
        acc[i][j] = __builtin_amdgcn_mfma_f32_16x16x32_bf16(af[i], bfv[j], acc[i][j], 0, 0, 0);
    __syncthreads();
  }

  // epilogue: D row = (l>>4)*4 + r, col = l&15
#pragma unroll
  for (int i = 0; i < 4; ++i) {
#pragma unroll
    for (int r = 0; r < 4; ++r) {
      const int m = bm0 + wm + i * 16 + (l >> 4) * 4 + r;
#pragma unroll
      for (int j = 0; j < 4; ++j) {
        const int n = bn0 + wn + j * 16 + lr;
        const float va = acc[i][j][r];
        if (EPI == 0) {
          ((u16*)outp)[(size_t)m * N + n] = f2bf(va);
        } else if (EPI == 1) {
          ((u16*)outp)[(size_t)m * N + n] = f2bf(gelu_f(va + bias[n]));
        } else {
          ((float*)outp)[(size_t)m * N + n] = va + bias[n] + resid[(size_t)m * N + n];
        }
      }
    }
  }
}

// ---------------- causal flash attention ----------------
// grid (32 qblocks, 32 bh). 4 waves * 16 q-rows, KVB=64, HD=64.
// K/V LDS tiles XOR-swizzled (granule ^= row&7) to kill 16-way bank conflicts.
__global__ __launch_bounds__(256) void attn(const u16* __restrict__ q,
                                            const u16* __restrict__ k,
                                            const u16* __restrict__ vt,
                                            u16* __restrict__ ctx, int ldq) {
  const int qb = blockIdx.x;
  const int bh = blockIdx.y;
  const int b = bh >> 4, h = bh & 15;
  const int t = threadIdx.x, w = t >> 6, l = t & 63;
  const int lr = l & 15, lg = l >> 4;

  __shared__ alignas(16) u16 Ksm[64 * 64];   // [kv][feat]  (swizzled)
  __shared__ alignas(16) u16 Vsm[64 * 64];   // [d][kv]     (swizzled)
  __shared__ alignas(16) u16 Psm[4][16 * 64];// per wave [q][kv] (swizzled)

  const int q0 = qb * 64 + w * 16;

  bf16x8 aq[2];
#pragma unroll
  for (int kc = 0; kc < 2; ++kc)
    aq[kc] = *(const bf16x8*)(q + (size_t)(b * 2048 + q0 + lr) * ldq + h * 64 + kc * 32 + lg * 8);

  f32x4 o[4];
#pragma unroll
  for (int j = 0; j < 4; ++j) o[j] = (f32x4){0.f, 0.f, 0.f, 0.f};
  float mrow[4], lrow[4];
#pragma unroll
  for (int r = 0; r < 4; ++r) { mrow[r] = -1e30f; lrow[r] = 0.f; }

  const int nkv = qb + 1;
  for (int it = 0; it < nkv; ++it) {
    const int kv0 = it * 64;
#pragma unroll
    for (int c = 0; c < 2; ++c) {
      const int lin = c * 256 + t;
      const int row = lin >> 3, g = lin & 7;
      const int gs = g ^ (row & 7);   // pre-swizzled global source (rule #21)
      gload_lds16(k + (size_t)(b * 2048 + kv0 + row) * ldq + h * 64 + gs * 8,
                  (char*)Ksm + lin * 16);
      gload_lds16(vt + (size_t)(bh * 64 + row) * 2048 + kv0 + gs * 8,
                  (char*)Vsm + lin * 16);
    }
    __syncthreads();

    // S = Q K^T  (D: row=q=(lg*4+r), col=kv=lr)
    f32x4 s[4];
#pragma unroll
    for (int nf = 0; nf < 4; ++nf) {
      f32x4 a = (f32x4){0.f, 0.f, 0.f, 0.f};
#pragma unroll
      for (int kc = 0; kc < 2; ++kc) {
        const int row = nf * 16 + lr;
        const int gr = (kc * 4 + lg) ^ (row & 7);
        const bf16x8 bk = *(const bf16x8*)(Ksm + row * 64 + gr * 8);
        a = __builtin_amdgcn_mfma_f32_16x16x32_bf16(aq[kc], bk, a, 0, 0, 0);
      }
      s[nf] = a;
    }

    // online softmax per q-row
#pragma unroll
    for (int r = 0; r < 4; ++r) {
      const int qa = q0 + lg * 4 + r;
      float pm = -1e30f;
#pragma unroll
      for (int nf = 0; nf < 4; ++nf) {
        const int kv = kv0 + nf * 16 + lr;
        const float sv = (kv <= qa) ? s[nf][r] * 0.125f : -1e30f;
        s[nf][r] = sv;
        pm = fmaxf(pm, sv);
      }
#pragma unroll
      for (int d = 1; d < 16; d <<= 1) pm = fmaxf(pm, __shfl_xor(pm, d));
      const float mnew = fmaxf(mrow[r], pm);
      const float alpha = exp2f((mrow[r] - mnew) * 1.44269504f);
      mrow[r] = mnew;
      float ps = 0.f;
#pragma unroll
      for (int nf = 0; nf < 4; ++nf) {
        const float p = exp2f((s[nf][r] - mnew) * 1.44269504f);
        s[nf][r] = p;
        ps += p;
      }
#pragma unroll
      for (int d = 1; d < 16; d <<= 1) ps += __shfl_xor(ps, d);
      lrow[r] = lrow[r] * alpha + ps;
#pragma unroll
      for (int j = 0; j < 4; ++j) o[j][r] = o[j][r] * alpha;
    }

    // P -> LDS (re-layout into MFMA A-fragment), swizzled same as K/V
    u16* pw = Psm[w];
#pragma unroll
    for (int r = 0; r < 4; ++r) {
      const int qrw = lg * 4 + r;
#pragma unroll
      for (int nf = 0; nf < 4; ++nf) {
        const int e = nf * 16 + lr;
        const int es = (((e >> 3) ^ (qrw & 7)) << 3) + (e & 7);
        pw[qrw * 64 + es] = f2bf(s[nf][r]);
      }
    }
    __syncthreads();

    // O += P V
#pragma unroll
    for (int kc = 0; kc < 2; ++kc) {
      const int gp = (kc * 4 + lg) ^ (lr & 7);
      const bf16x8 ap = *(const bf16x8*)(pw + lr * 64 + gp * 8);
#pragma unroll
      for (int j = 0; j < 4; ++j) {
        const int row = j * 16 + lr;
        const int gv = (kc * 4 + lg) ^ (row & 7);
        const bf16x8 bv = *(const bf16x8*)(Vsm + row * 64 + gv * 8);
        o[j] = __builtin_amdgcn_mfma_f32_16x16x32_bf16(ap, bv, o[j], 0, 0, 0);
      }
    }
    __syncthreads();
  }

  // write ctx (bf16), normalized
#pragma unroll
  for (int j = 0; j < 4; ++j) {
#pragma unroll
    for (int r = 0; r < 4; ++r) {
      const float val = o[j][r] / lrow[r];
      ctx[(size_t)(b * 2048 + q0 + lg * 4 + r) * 1024 + h * 64 + j * 16 + lr] = f2bf(val);
    }
  }
}

// ---------------- host launch ----------------
extern "C" void kernel_launch(void* const* d_in, const int* in_sizes, int n_in,
                              void* d_out, int out_size, void* d_ws, size_t ws_size,
                              hipStream_t stream) {
  const float* x  = (const float*)d_in[0];
  const float* Wq = (const float*)d_in[1];
  const float* Wk = (const float*)d_in[2];
  const float* Wv = (const float*)d_in[3];
  const float* Wo = (const float*)d_in[4];
  const float* bo = (const float*)d_in[5];
  const float* W1 = (const float*)d_in[6];
  const float* b1 = (const float*)d_in[7];
  const float* W2 = (const float*)d_in[8];
  const float* b2 = (const float*)d_in[9];
  const float* g1 = (const float*)d_in[10];
  const float* s1 = (const float*)d_in[11];
  const float* g2 = (const float*)d_in[12];
  const float* s2 = (const float*)d_in[13];

  char* ws = (char*)d_ws;
  const size_t MB = 1ull << 20;
  u16*  h1    = (u16*)(ws + 0);          // 8MB   LN out (reused for LN2 out)
  u16*  wqkvT = (u16*)(ws + 8 * MB);     // 6MB   [3072,1024]
  u16*  woT   = (u16*)(ws + 14 * MB);    // 2MB   [1024,1024]
  u16*  w1T   = (u16*)(ws + 16 * MB);    // 8MB   [4096,1024]
  u16*  w2T   = (u16*)(ws + 24 * MB);    // 8MB   [1024,4096]
  u16*  qkv   = (u16*)(ws + 32 * MB);    // 24MB  [4096,3072]
  u16*  vtb   = (u16*)(ws + 56 * MB);    // 8MB   [2048,2048]
  u16*  ctx   = (u16*)(ws + 64 * MB);    // 8MB   [4096,1024]
  float* x2   = (float*)(ws + 72 * MB);  // 16MB  [4096,1024] f32
  u16*  ff1   = (u16*)(ws + 32 * MB);    // 32MB  alias over qkv+vtb (dead by then)

  const dim3 blk(256);

  wtrans<<<dim3(32, 32),  blk, 0, stream>>>(Wq, wqkvT,                1024, 1024);
  wtrans<<<dim3(32, 32),  blk, 0, stream>>>(Wk, wqkvT + 1024 * 1024,  1024, 1024);
  wtrans<<<dim3(32, 32),  blk, 0, stream>>>(Wv, wqkvT + 2048 * 1024,  1024, 1024);
  wtrans<<<dim3(32, 32),  blk, 0, stream>>>(Wo, woT,                  1024, 1024);
  wtrans<<<dim3(128, 32), blk, 0, stream>>>(W1, w1T, 1024, 4096);
  wtrans<<<dim3(32, 128), blk, 0, stream>>>(W2, w2T, 4096, 1024);

  ln_bf16<<<dim3(4096), blk, 0, stream>>>(x, g1, s1, h1);

  gemm_bt<0><<<dim3(32, 24), blk, 0, stream>>>(h1, wqkvT, nullptr, nullptr,
                                               (void*)qkv, 4096, 3072, 1024);

  vtrans<<<dim3(64, 2, 32), blk, 0, stream>>>(qkv + 2048, vtb, 3072);

  attn<<<dim3(32, 32), blk, 0, stream>>>(qkv, qkv + 1024, vtb, ctx, 3072);

  gemm_bt<2><<<dim3(32, 8), blk, 0, stream>>>(ctx, woT, bo, x,
                                              (void*)x2, 4096, 1024, 1024);

  ln_bf16<<<dim3(4096), blk, 0, stream>>>(x2, g2, s2, h1);

  gemm_bt<1><<<dim3(32, 32), blk, 0, stream>>>(h1, w1T, b1, nullptr,
                                               (void*)ff1, 4096, 4096, 1024);

  gemm_bt<2><<<dim3(32, 8), blk, 0, stream>>>(ff1, w2T, b2, x2,
                                              d_out, 4096, 1024, 4096);
}